// Round 5
// baseline (361.553 us; speedup 1.0000x reference)
//
#include <hip/hip_runtime.h>
#include <hip/hip_fp16.h>
#include <stdint.h>

// Problem constants
#define B_ 32
#define T_ 2048
#define D_ 512
#define U_ 512
#define M_ (B_ * T_)
#define MAXC 4

typedef _Float16 half8   __attribute__((ext_vector_type(8)));
typedef float   floatx4  __attribute__((ext_vector_type(4)));
typedef float   floatx16 __attribute__((ext_vector_type(16)));

__device__ __forceinline__ float tanh_fast(float x) {
    float ax = fabsf(x);
    float e  = __expf(2.0f * ax);
    float t  = 1.0f - 2.0f / (e + 1.0f);
    return copysignf(t, x);
}

// ---------------- k_prep: fused {W1 -> W1T fp16 transpose} + {w2q = query @ W2} ----
// (validated r2/r3) blocks 0..63: transpose; blocks 64..191: w2q
__global__ __launch_bounds__(256)
void k_prep(const float* __restrict__ W1, const float* __restrict__ query,
            const float* __restrict__ W2, _Float16* __restrict__ W1T,
            float* __restrict__ w2q) {
    const int bid = blockIdx.x;
    const int tid = threadIdx.x;
    if (bid < 64) {
        __shared__ float tile[64][65];
        const int bx = bid & 7;          // k-tile
        const int by = bid >> 3;         // n-tile
        const int k0 = bx * 64, n0 = by * 64;
        const int tx = tid & 63;
        const int ty = tid >> 6;         // 0..3
#pragma unroll
        for (int i = 0; i < 16; ++i) {
            int r = ty * 16 + i;
            tile[r][tx] = W1[(size_t)(k0 + r) * U_ + n0 + tx];
        }
        __syncthreads();
#pragma unroll
        for (int i = 0; i < 16; ++i) {
            int r = ty * 16 + i;
            W1T[(size_t)(n0 + r) * D_ + k0 + tx] = (_Float16)tile[tx][r];
        }
    } else {
        __shared__ float sq[D_];
        __shared__ float part[128];
        const int id = bid - 64;
        const int b  = id >> 2;          // 0..31
        const int nq = id & 3;           // n-chunk of 128
        sq[tid]       = query[b * D_ + tid];
        sq[tid + 256] = query[b * D_ + tid + 256];
        __syncthreads();
        const int n  = nq * 128 + (tid & 127);
        const int dh = tid >> 7;         // 0/1 -> d-half
        float acc = 0.f;
        const int d0 = dh * 256;
#pragma unroll 16
        for (int d = d0; d < d0 + 256; ++d)
            acc = fmaf(sq[d], W2[(size_t)d * U_ + n], acc);
        if (dh == 1) part[tid & 127] = acc;
        __syncthreads();
        if (dh == 0) w2q[b * U_ + n] = acc + part[tid];
    }
}

// ---------------- k_gemm_u: zero-LDS, zero-barrier streaming GEMM ----------------
// 2048 waves, each owns 32 rows: full-K A tile in 128 VGPRs (fp16), then 16
// n-groups of 32 cols streaming B-frags from W1T (L1-shared). No __syncthreads.
__global__ __launch_bounds__(256, 2)
void k_gemm_u(const float* __restrict__ value,
              const _Float16* __restrict__ W1T,  // [N=512][K=512] fp16
              const float* __restrict__ w2q,     // [32][512]
              const float* __restrict__ Vv,      // [512]
              float* __restrict__ u_out) {       // [65536]
    const int tid  = threadIdx.x;
    const int wave = tid >> 6;
    const int lane = tid & 63;
    const int l31  = lane & 31;
    const int hi   = lane >> 5;                  // 0/1 -> k-half of the 16-k step
    const int gw   = blockIdx.x * 4 + wave;      // 0..2047
    const int m0   = gw * 32;
    const int b    = m0 >> 11;

    // ---- A preload: row (m0+l31), cols {s*16 + hi*8 .. +8} for s=0..31.
    // Each fp32 of value is read by exactly one lane. 64-B granules per row.
    half8 af[32];
    const float* arow = value + (size_t)(m0 + l31) * D_ + hi * 8;
#pragma unroll
    for (int sb = 0; sb < 4; ++sb) {             // 4 batches x 8 steps: 16 loads in flight
        floatx4 t0[8], t1[8];
#pragma unroll
        for (int s8 = 0; s8 < 8; ++s8) {
            const float* p = arow + (sb * 8 + s8) * 16;
            t0[s8] = *(const floatx4*)p;
            t1[s8] = *(const floatx4*)(p + 4);
        }
#pragma unroll
        for (int s8 = 0; s8 < 8; ++s8) {
            half8 h;
#pragma unroll
            for (int j = 0; j < 4; ++j) {
                h[j]     = (_Float16)t0[s8][j];
                h[4 + j] = (_Float16)t1[s8][j];
            }
            af[sb * 8 + s8] = h;
        }
    }

    // ---- n-group loop: 16 groups x 32 cols; B-frags streamed, acc per group.
    float u_acc[16];
#pragma unroll
    for (int r = 0; r < 16; ++r) u_acc[r] = 0.f;

    for (int g = 0; g < 16; ++g) {
        const int n = g * 32 + l31;
        const _Float16* bp = W1T + (size_t)n * D_ + hi * 8;

        floatx16 acc;
#pragma unroll
        for (int r = 0; r < 16; ++r) acc[r] = 0.f;

#pragma unroll
        for (int s = 0; s < 32; ++s) {
            const half8 bf = *(const half8*)(bp + s * 16);
            acc = __builtin_amdgcn_mfma_f32_32x32x16_f16(af[s], bf, acc, 0, 0, 0);
        }

        const float w2 = w2q[b * U_ + n];
        const float vv = Vv[n];
#pragma unroll
        for (int r = 0; r < 16; ++r)
            u_acc[r] += vv * tanh_fast(acc[r] + w2);
    }

    // ---- reduce over the 32 column-lanes (xor 1..16 stays within each 32-half)
#pragma unroll
    for (int off = 1; off < 32; off <<= 1)
#pragma unroll
        for (int r = 0; r < 16; ++r)
            u_acc[r] += __shfl_xor(u_acc[r], off, 64);

    if (l31 == 0) {
#pragma unroll
        for (int r = 0; r < 16; ++r) {
            const int row = (r & 3) + 8 * (r >> 2) + 4 * hi;   // C/D row map (validated r4)
            u_out[m0 + row] = u_acc[r];
        }
    }
}

// ---------------- k_post: softmax + top-4 + joint exact rescore + gather -------
// (validated r2/r3 form, reads u directly)
__global__ __launch_bounds__(256)
void k_post(const float* __restrict__ u, const int* __restrict__ mask,
            const float* __restrict__ value, const float* __restrict__ W1,
            const float* __restrict__ w2q, const float* __restrict__ Vv,
            float* __restrict__ a_out, float* __restrict__ ctx_out) {
    __shared__ float sx[T_];
    __shared__ float rv[4];
    __shared__ int   ri[4];
    __shared__ float s_scalar;
    __shared__ int   s_cand[MAXC];
    __shared__ float s_score[MAXC];
    __shared__ __align__(16) float vrows[MAXC][D_];
    __shared__ int   s_t;

    const int b = blockIdx.x;
    const int tid = threadIdx.x;
    const int wave = tid >> 6, lane = tid & 63;

#pragma unroll
    for (int i = 0; i < 8; ++i) {
        const int t = tid * 8 + i;
        float x = u[b * T_ + t];
        if (mask[b * T_ + t] == 0) x = -1e20f;
        sx[t] = x;
    }
    __syncthreads();

    for (int r = 0; r < MAXC; ++r) {
        float v = -INFINITY; int vi = 0;
#pragma unroll
        for (int i = 0; i < 8; ++i) {
            const int t = tid * 8 + i;
            const float x = sx[t];
            if (x > v) { v = x; vi = t; }
        }
        for (int off = 32; off > 0; off >>= 1) {
            const float ov = __shfl_down(v, off, 64);
            const int   oi = __shfl_down(vi, off, 64);
            if (ov > v || (ov == v && oi < vi)) { v = ov; vi = oi; }
        }
        if (lane == 0) { rv[wave] = v; ri[wave] = vi; }
        __syncthreads();
        if (tid == 0) {
            float bv = rv[0]; int bi = ri[0];
            for (int w = 1; w < 4; ++w)
                if (rv[w] > bv || (rv[w] == bv && ri[w] < bi)) { bv = rv[w]; bi = ri[w]; }
            s_cand[r] = bi;
            if (r == 0) s_scalar = bv;
            sx[bi] = -INFINITY;
        }
        __syncthreads();
    }
    const float mx = s_scalar;

    float zloc = 0.f;
    float evals[8];
#pragma unroll
    for (int i = 0; i < 8; ++i) {
        const int t = tid * 8 + i;
        float x = u[b * T_ + t];
        if (mask[b * T_ + t] == 0) x = -1e20f;
        const float e = __expf(x - mx);
        evals[i] = e;
        zloc += e;
    }
    for (int off = 32; off > 0; off >>= 1) zloc += __shfl_down(zloc, off, 64);
    if (lane == 0) rv[wave] = zloc;
    __syncthreads();
    if (tid == 0) s_scalar = 1.0f / (rv[0] + rv[1] + rv[2] + rv[3]);
    __syncthreads();
    const float rz = s_scalar;
#pragma unroll
    for (int i = 0; i < 8; ++i) {
        const int t = tid * 8 + i;
        a_out[b * T_ + t] = evals[i] * rz;
    }

    // ---- joint exact fp32 rescore of the 4 candidates (one pass over W1) ----
#pragma unroll
    for (int ci = 0; ci < MAXC; ++ci) {
        const int t = s_cand[ci];
        vrows[ci][tid]       = value[((size_t)b * T_ + t) * D_ + tid];
        vrows[ci][tid + 256] = value[((size_t)b * T_ + t) * D_ + tid + 256];
    }
    __syncthreads();

    float dots[2][MAXC];
#pragma unroll
    for (int j = 0; j < 2; ++j)
#pragma unroll
        for (int ci = 0; ci < MAXC; ++ci) dots[j][ci] = 0.f;

    for (int d4 = 0; d4 < D_; d4 += 4) {
        floatx4 vr[MAXC];
#pragma unroll
        for (int ci = 0; ci < MAXC; ++ci)
            vr[ci] = *(const floatx4*)(&vrows[ci][d4]);
#pragma unroll
        for (int k = 0; k < 4; ++k) {
            const float w0 = W1[(size_t)(d4 + k) * U_ + tid];
            const float w1 = W1[(size_t)(d4 + k) * U_ + tid + 256];
#pragma unroll
            for (int ci = 0; ci < MAXC; ++ci) {
                dots[0][ci] = fmaf(vr[ci][k], w0, dots[0][ci]);
                dots[1][ci] = fmaf(vr[ci][k], w1, dots[1][ci]);
            }
        }
    }
    float sc[MAXC];
#pragma unroll
    for (int ci = 0; ci < MAXC; ++ci) {
        const float n0v = Vv[tid]       * tanhf(dots[0][ci] + w2q[b * U_ + tid]);
        const float n1v = Vv[tid + 256] * tanhf(dots[1][ci] + w2q[b * U_ + tid + 256]);
        sc[ci] = n0v + n1v;
    }
#pragma unroll
    for (int ci = 0; ci < MAXC; ++ci)
        for (int off = 32; off > 0; off >>= 1)
            sc[ci] += __shfl_down(sc[ci], off, 64);
    __syncthreads();
    if (lane == 0) {
#pragma unroll
        for (int ci = 0; ci < MAXC; ++ci)
            vrows[ci][wave] = sc[ci];
    }
    __syncthreads();
    if (tid == 0) {
#pragma unroll
        for (int ci = 0; ci < MAXC; ++ci) {
            const int t = s_cand[ci];
            float s = vrows[ci][0] + vrows[ci][1] + vrows[ci][2] + vrows[ci][3];
            if (mask[b * T_ + t] == 0) s = -1e20f;
            s_score[ci] = s;
        }
        float bv = s_score[0]; int bt = s_cand[0];
        for (int i = 1; i < MAXC; ++i) {
            if (s_score[i] > bv || (s_score[i] == bv && s_cand[i] < bt)) {
                bv = s_score[i]; bt = s_cand[i];
            }
        }
        s_t = bt;
    }
    __syncthreads();

    const int t = s_t;
    ctx_out[b * D_ + tid]       = value[((size_t)b * T_ + t) * D_ + tid];
    ctx_out[b * D_ + tid + 256] = value[((size_t)b * T_ + t) * D_ + tid + 256];
}

extern "C" void kernel_launch(void* const* d_in, const int* in_sizes, int n_in,
                              void* d_out, int out_size, void* d_ws, size_t ws_size,
                              hipStream_t stream) {
    const float* value = (const float*)d_in[0];   // [32,2048,512]
    const float* query = (const float*)d_in[1];   // [32,512]
    const int*   mask  = (const int*)d_in[2];     // [32,2048]
    const float* W1    = (const float*)d_in[3];   // [512,512]
    const float* W2    = (const float*)d_in[4];   // [512,512]
    const float* Vv    = (const float*)d_in[5];   // [512]

    char* ws = (char*)d_ws;
    _Float16* W1T  = (_Float16*)ws;                    // 524,288 B
    float*    w2q  = (float*)(ws + 524288);            //  65,536 B
    float*    u_ws = (float*)(ws + 524288 + 65536);    // 262,144 B

    float* ctx_out = (float*)d_out;              // [32,512]
    float* a_out   = (float*)d_out + B_ * D_;    // [32,2048]

    hipLaunchKernelGGL(k_prep,   dim3(192), dim3(256), 0, stream,
                       W1, query, W2, W1T, w2q);
    hipLaunchKernelGGL(k_gemm_u, dim3(512), dim3(256), 0, stream,
                       value, W1T, w2q, Vv, u_ws);
    hipLaunchKernelGGL(k_post,   dim3(32), dim3(256), 0, stream,
                       u_ws, mask, value, W1, w2q, Vv, a_out, ctx_out);
}

// Round 6
// 312.088 us; speedup vs baseline: 1.1585x; 1.1585x over previous
//
#include <hip/hip_runtime.h>
#include <hip/hip_fp16.h>
#include <stdint.h>

// Problem constants
#define B_ 32
#define T_ 2048
#define D_ 512
#define U_ 512
#define M_ (B_ * T_)
#define MAXC 4

// GEMM: 64 rows/block, full-K A in LDS ((k-chunk,row)-major, conflict-free),
// one barrier, B streamed from L2-resident W1T, 2 blocks/CU overlap.
#define ROWS 64

typedef _Float16 half8   __attribute__((ext_vector_type(8)));
typedef float   floatx4  __attribute__((ext_vector_type(4)));
typedef float   floatx16 __attribute__((ext_vector_type(16)));

__device__ __forceinline__ float tanh_fast(float x) {
    float ax = fabsf(x);
    float e  = __expf(2.0f * ax);
    float t  = 1.0f - 2.0f / (e + 1.0f);
    return copysignf(t, x);
}

// ---------------- k_prep: fused {W1 -> W1T fp16 transpose} + {w2q = query @ W2} ----
__global__ __launch_bounds__(256)
void k_prep(const float* __restrict__ W1, const float* __restrict__ query,
            const float* __restrict__ W2, _Float16* __restrict__ W1T,
            float* __restrict__ w2q) {
    const int bid = blockIdx.x;
    const int tid = threadIdx.x;
    if (bid < 64) {
        __shared__ float tile[64][65];
        const int bx = bid & 7;          // k-tile
        const int by = bid >> 3;         // n-tile
        const int k0 = bx * 64, n0 = by * 64;
        const int tx = tid & 63;
        const int ty = tid >> 6;         // 0..3
#pragma unroll
        for (int i = 0; i < 16; ++i) {
            int r = ty * 16 + i;
            tile[r][tx] = W1[(size_t)(k0 + r) * U_ + n0 + tx];
        }
        __syncthreads();
#pragma unroll
        for (int i = 0; i < 16; ++i) {
            int r = ty * 16 + i;
            W1T[(size_t)(n0 + r) * D_ + k0 + tx] = (_Float16)tile[tx][r];
        }
    } else {
        __shared__ float sq[D_];
        __shared__ float part[128];
        const int id = bid - 64;
        const int b  = id >> 2;          // 0..31
        const int nq = id & 3;           // n-chunk of 128
        sq[tid]       = query[b * D_ + tid];
        sq[tid + 256] = query[b * D_ + tid + 256];
        __syncthreads();
        const int n  = nq * 128 + (tid & 127);
        const int dh = tid >> 7;         // 0/1 -> d-half
        float acc = 0.f;
        const int d0 = dh * 256;
#pragma unroll 16
        for (int d = d0; d < d0 + 256; ++d)
            acc = fmaf(sq[d], W2[(size_t)d * U_ + n], acc);
        if (dh == 1) part[tid & 127] = acc;
        __syncthreads();
        if (dh == 0) w2q[b * U_ + n] = acc + part[tid];
    }
}

// ---------------- k_gemm_u: one-barrier GEMM + tanh + V-dot -> u[b,t] ----------------
// LDS layout: sA[c_chunk][row][8 halves], c_chunk = s*2+hi covers k = c*8..c*8+8.
// Stage: wave w loads rows 0..63 (lane=row) cols [64w,64w+64); stores are
// lane-contiguous 1KB per instr (0 conflicts). Read af: lane-contiguous (0 conflicts).
__global__ __launch_bounds__(512, 4)
void k_gemm_u(const float* __restrict__ value,
              const _Float16* __restrict__ W1T,  // [N=512][K=512] fp16
              const float* __restrict__ w2q,     // [32][512]
              const float* __restrict__ Vv,      // [512]
              float* __restrict__ u_out) {       // [65536]
    __shared__ __align__(16) _Float16 sA[64 * 64 * 8];   // 65,536 B
    __shared__ float sRed[8][ROWS];                      //  2,048 B

    const int tid  = threadIdx.x;
    const int wave = tid >> 6;
    const int lane = tid & 63;
    const int l31  = lane & 31;
    const int hi   = lane >> 5;              // 0/1
    const int m0   = blockIdx.x * ROWS;
    const int b    = m0 >> 11;

    // ---- stage A (single shot, full K): lane = row, wave = 64-col slab
    {
        const float* src = value + (size_t)(m0 + lane) * D_ + wave * 64;
        floatx4 r[16];
#pragma unroll
        for (int i = 0; i < 16; ++i) r[i] = *(const floatx4*)(src + i * 4);
#pragma unroll
        for (int j = 0; j < 8; ++j) {
            half8 h;
#pragma unroll
            for (int q = 0; q < 4; ++q) {
                h[q]     = (_Float16)r[2 * j][q];
                h[4 + q] = (_Float16)r[2 * j + 1][q];
            }
            *(half8*)(&sA[((wave * 8 + j) * 64 + lane) * 8]) = h;
        }
    }
    __syncthreads();   // the only staging barrier; drain = HBM BW time,
                       // overlapped by the co-resident block's compute phase

    float u_acc0[16], u_acc1[16];
#pragma unroll
    for (int r = 0; r < 16; ++r) { u_acc0[r] = 0.f; u_acc1[r] = 0.f; }

#pragma unroll
    for (int g = 0; g < 2; ++g) {
        const int n = wave * 64 + g * 32 + l31;
        const _Float16* bp = W1T + (size_t)n * D_ + hi * 8;

        floatx16 acc0, acc1;
#pragma unroll
        for (int r = 0; r < 16; ++r) { acc0[r] = 0.f; acc1[r] = 0.f; }

#pragma unroll
        for (int s = 0; s < 32; ++s) {
            const half8 bf  = *(const half8*)(bp + s * 16);
            const int   cc  = (s * 2 + hi) * 64;     // c_chunk base
            const half8 af0 = *(const half8*)(&sA[(cc + l31) * 8]);
            const half8 af1 = *(const half8*)(&sA[(cc + 32 + l31) * 8]);
            acc0 = __builtin_amdgcn_mfma_f32_32x32x16_f16(af0, bf, acc0, 0, 0, 0);
            acc1 = __builtin_amdgcn_mfma_f32_32x32x16_f16(af1, bf, acc1, 0, 0, 0);
        }

        const float w2 = w2q[b * U_ + n];
        const float vv = Vv[n];
#pragma unroll
        for (int r = 0; r < 16; ++r) {
            u_acc0[r] += vv * tanh_fast(acc0[r] + w2);
            u_acc1[r] += vv * tanh_fast(acc1[r] + w2);
        }
    }

    // ---- reduce over the 32 column-lanes (xor 1..16 stays within each 32-half)
#pragma unroll
    for (int off = 1; off < 32; off <<= 1)
#pragma unroll
        for (int r = 0; r < 16; ++r) {
            u_acc0[r] += __shfl_xor(u_acc0[r], off, 64);
            u_acc1[r] += __shfl_xor(u_acc1[r], off, 64);
        }

    if (l31 == 0) {
#pragma unroll
        for (int r = 0; r < 16; ++r) {
            const int row = (r & 3) + 8 * (r >> 2) + 4 * hi;  // C/D row map (validated)
            sRed[wave][row]      = u_acc0[r];
            sRed[wave][32 + row] = u_acc1[r];
        }
    }
    __syncthreads();
    if (tid < ROWS) {
        float s = 0.f;
#pragma unroll
        for (int w = 0; w < 8; ++w) s += sRed[w][tid];
        u_out[m0 + tid] = s;
    }
}

// ---------------- k_post: softmax + top-4 + joint exact rescore + gather -------
__global__ __launch_bounds__(256)
void k_post(const float* __restrict__ u, const int* __restrict__ mask,
            const float* __restrict__ value, const float* __restrict__ W1,
            const float* __restrict__ w2q, const float* __restrict__ Vv,
            float* __restrict__ a_out, float* __restrict__ ctx_out) {
    __shared__ float sx[T_];
    __shared__ float rv[4];
    __shared__ int   ri[4];
    __shared__ float s_scalar;
    __shared__ int   s_cand[MAXC];
    __shared__ float s_score[MAXC];
    __shared__ __align__(16) float vrows[MAXC][D_];
    __shared__ int   s_t;

    const int b = blockIdx.x;
    const int tid = threadIdx.x;
    const int wave = tid >> 6, lane = tid & 63;

#pragma unroll
    for (int i = 0; i < 8; ++i) {
        const int t = tid * 8 + i;
        float x = u[b * T_ + t];
        if (mask[b * T_ + t] == 0) x = -1e20f;
        sx[t] = x;
    }
    __syncthreads();

    for (int r = 0; r < MAXC; ++r) {
        float v = -INFINITY; int vi = 0;
#pragma unroll
        for (int i = 0; i < 8; ++i) {
            const int t = tid * 8 + i;
            const float x = sx[t];
            if (x > v) { v = x; vi = t; }
        }
        for (int off = 32; off > 0; off >>= 1) {
            const float ov = __shfl_down(v, off, 64);
            const int   oi = __shfl_down(vi, off, 64);
            if (ov > v || (ov == v && oi < vi)) { v = ov; vi = oi; }
        }
        if (lane == 0) { rv[wave] = v; ri[wave] = vi; }
        __syncthreads();
        if (tid == 0) {
            float bv = rv[0]; int bi = ri[0];
            for (int w = 1; w < 4; ++w)
                if (rv[w] > bv || (rv[w] == bv && ri[w] < bi)) { bv = rv[w]; bi = ri[w]; }
            s_cand[r] = bi;
            if (r == 0) s_scalar = bv;
            sx[bi] = -INFINITY;
        }
        __syncthreads();
    }
    const float mx = s_scalar;

    float zloc = 0.f;
    float evals[8];
#pragma unroll
    for (int i = 0; i < 8; ++i) {
        const int t = tid * 8 + i;
        float x = u[b * T_ + t];
        if (mask[b * T_ + t] == 0) x = -1e20f;
        const float e = __expf(x - mx);
        evals[i] = e;
        zloc += e;
    }
    for (int off = 32; off > 0; off >>= 1) zloc += __shfl_down(zloc, off, 64);
    if (lane == 0) rv[wave] = zloc;
    __syncthreads();
    if (tid == 0) s_scalar = 1.0f / (rv[0] + rv[1] + rv[2] + rv[3]);
    __syncthreads();
    const float rz = s_scalar;
#pragma unroll
    for (int i = 0; i < 8; ++i) {
        const int t = tid * 8 + i;
        a_out[b * T_ + t] = evals[i] * rz;
    }

    // ---- joint exact fp32 rescore of the 4 candidates (one pass over W1) ----
#pragma unroll
    for (int ci = 0; ci < MAXC; ++ci) {
        const int t = s_cand[ci];
        vrows[ci][tid]       = value[((size_t)b * T_ + t) * D_ + tid];
        vrows[ci][tid + 256] = value[((size_t)b * T_ + t) * D_ + tid + 256];
    }
    __syncthreads();

    float dots[2][MAXC];
#pragma unroll
    for (int j = 0; j < 2; ++j)
#pragma unroll
        for (int ci = 0; ci < MAXC; ++ci) dots[j][ci] = 0.f;

    for (int d4 = 0; d4 < D_; d4 += 4) {
        floatx4 vr[MAXC];
#pragma unroll
        for (int ci = 0; ci < MAXC; ++ci)
            vr[ci] = *(const floatx4*)(&vrows[ci][d4]);
#pragma unroll
        for (int k = 0; k < 4; ++k) {
            const float w0 = W1[(size_t)(d4 + k) * U_ + tid];
            const float w1 = W1[(size_t)(d4 + k) * U_ + tid + 256];
#pragma unroll
            for (int ci = 0; ci < MAXC; ++ci) {
                dots[0][ci] = fmaf(vr[ci][k], w0, dots[0][ci]);
                dots[1][ci] = fmaf(vr[ci][k], w1, dots[1][ci]);
            }
        }
    }
    float sc[MAXC];
#pragma unroll
    for (int ci = 0; ci < MAXC; ++ci) {
        const float n0v = Vv[tid]       * tanhf(dots[0][ci] + w2q[b * U_ + tid]);
        const float n1v = Vv[tid + 256] * tanhf(dots[1][ci] + w2q[b * U_ + tid + 256]);
        sc[ci] = n0v + n1v;
    }
#pragma unroll
    for (int ci = 0; ci < MAXC; ++ci)
        for (int off = 32; off > 0; off >>= 1)
            sc[ci] += __shfl_down(sc[ci], off, 64);
    __syncthreads();
    if (lane == 0) {
#pragma unroll
        for (int ci = 0; ci < MAXC; ++ci)
            vrows[ci][wave] = sc[ci];
    }
    __syncthreads();
    if (tid == 0) {
#pragma unroll
        for (int ci = 0; ci < MAXC; ++ci) {
            const int t = s_cand[ci];
            float s = vrows[ci][0] + vrows[ci][1] + vrows[ci][2] + vrows[ci][3];
            if (mask[b * T_ + t] == 0) s = -1e20f;
            s_score[ci] = s;
        }
        float bv = s_score[0]; int bt = s_cand[0];
        for (int i = 1; i < MAXC; ++i) {
            if (s_score[i] > bv || (s_score[i] == bv && s_cand[i] < bt)) {
                bv = s_score[i]; bt = s_cand[i];
            }
        }
        s_t = bt;
    }
    __syncthreads();

    const int t = s_t;
    ctx_out[b * D_ + tid]       = value[((size_t)b * T_ + t) * D_ + tid];
    ctx_out[b * D_ + tid + 256] = value[((size_t)b * T_ + t) * D_ + tid + 256];
}

extern "C" void kernel_launch(void* const* d_in, const int* in_sizes, int n_in,
                              void* d_out, int out_size, void* d_ws, size_t ws_size,
                              hipStream_t stream) {
    const float* value = (const float*)d_in[0];   // [32,2048,512]
    const float* query = (const float*)d_in[1];   // [32,512]
    const int*   mask  = (const int*)d_in[2];     // [32,2048]
    const float* W1    = (const float*)d_in[3];   // [512,512]
    const float* W2    = (const float*)d_in[4];   // [512,512]
    const float* Vv    = (const float*)d_in[5];   // [512]

    char* ws = (char*)d_ws;
    _Float16* W1T  = (_Float16*)ws;                    // 524,288 B
    float*    w2q  = (float*)(ws + 524288);            //  65,536 B
    float*    u_ws = (float*)(ws + 524288 + 65536);    // 262,144 B

    float* ctx_out = (float*)d_out;              // [32,512]
    float* a_out   = (float*)d_out + B_ * D_;    // [32,2048]

    hipLaunchKernelGGL(k_prep,   dim3(192), dim3(256), 0, stream,
                       W1, query, W2, W1T, w2q);
    hipLaunchKernelGGL(k_gemm_u, dim3(M_ / ROWS), dim3(512), 0, stream,
                       value, W1T, w2q, Vv, u_ws);
    hipLaunchKernelGGL(k_post,   dim3(32), dim3(256), 0, stream,
                       u_ws, mask, value, W1, w2q, Vv, a_out, ctx_out);
}

// Round 7
// 310.289 us; speedup vs baseline: 1.1652x; 1.0058x over previous
//
#include <hip/hip_runtime.h>
#include <hip/hip_fp16.h>
#include <stdint.h>

// Problem constants
#define B_ 32
#define T_ 2048
#define D_ 512
#define U_ 512
#define M_ (B_ * T_)
#define MAXC 4

// GEMM: 256-thr blocks (4 waves), 64 rows x 128 cols, NSPLIT=4.
// A: full-K in LDS, (k-chunk,row)-major (validated r6, 0 conflicts), ONE barrier.
// B: per-wave 32 cols in registers (breg[32], validated r4), pre-packed W1P.
#define NSPLIT 4

typedef _Float16 half8   __attribute__((ext_vector_type(8)));
typedef float   floatx4  __attribute__((ext_vector_type(4)));
typedef float   floatx16 __attribute__((ext_vector_type(16)));

__device__ __forceinline__ float tanh_fast(float x) {
    float ax = fabsf(x);
    float e  = __expf(2.0f * ax);
    float t  = 1.0f - 2.0f / (e + 1.0f);
    return copysignf(t, x);
}

// ---------------- k_prep: {W1 -> W1P packed fp16} + {w2q = query @ W2} ----------------
// W1P layout: for n-group g=n>>5, chunk c=k>>3, nl=n&31, j=k&7:
//   W1P[g*16384 + c*256 + nl*8 + j]  -> breg loads are lane-contiguous 1KB.
__global__ __launch_bounds__(256)
void k_prep(const float* __restrict__ W1, const float* __restrict__ query,
            const float* __restrict__ W2, _Float16* __restrict__ W1P,
            float* __restrict__ w2q) {
    const int bid = blockIdx.x;
    const int tid = threadIdx.x;
    if (bid < 64) {
        __shared__ float tile[64][65];
        const int bx = bid & 7;          // k-tile
        const int by = bid >> 3;         // n-tile
        const int k0 = bx * 64, n0 = by * 64;
        const int tx = tid & 63;
        const int ty = tid >> 6;         // 0..3
#pragma unroll
        for (int i = 0; i < 16; ++i) {
            int r = ty * 16 + i;
            tile[r][tx] = W1[(size_t)(k0 + r) * U_ + n0 + tx];
        }
        __syncthreads();
#pragma unroll
        for (int i = 0; i < 16; ++i) {
            int r = ty * 16 + i;           // n = n0 + r, k = k0 + tx
            const int n = n0 + r, k = k0 + tx;
            const int idx = (n >> 5) * 16384 + (k >> 3) * 256 + (n & 31) * 8 + (k & 7);
            W1P[idx] = (_Float16)tile[tx][r];
        }
    } else {
        __shared__ float sq[D_];
        __shared__ float part[128];
        const int id = bid - 64;
        const int b  = id >> 2;          // 0..31
        const int nq = id & 3;           // n-chunk of 128
        sq[tid]       = query[b * D_ + tid];
        sq[tid + 256] = query[b * D_ + tid + 256];
        __syncthreads();
        const int n  = nq * 128 + (tid & 127);
        const int dh = tid >> 7;         // 0/1 -> d-half
        float acc = 0.f;
        const int d0 = dh * 256;
#pragma unroll 16
        for (int d = d0; d < d0 + 256; ++d)
            acc = fmaf(sq[d], W2[(size_t)d * U_ + n], acc);
        if (dh == 1) part[tid & 127] = acc;
        __syncthreads();
        if (dh == 0) w2q[b * U_ + n] = acc + part[tid];
    }
}

// ---------------- k_gemm_u: one-barrier, reg-B, LDS-A GEMM -> u_part ----------------
__global__ __launch_bounds__(256, 2)
void k_gemm_u(const float* __restrict__ value,
              const _Float16* __restrict__ W1P,  // packed (see k_prep)
              const float* __restrict__ w2q,     // [32][512]
              const float* __restrict__ Vv,      // [512]
              float* __restrict__ u_part) {      // [4][65536]
    __shared__ __align__(16) _Float16 sA[64 * 64 * 8];   // 65,536 B: [c][row][8]
    __shared__ float sRed[4][64];

    const int tid  = threadIdx.x;
    const int wave = tid >> 6;               // 0..3
    const int lane = tid & 63;
    const int l31  = lane & 31;
    const int hi   = lane >> 5;              // 0/1
    const int bx   = blockIdx.x;
    // swizzle: 4 slice-twins of a row-group land on the SAME XCD (bx%8 equal),
    // within a 32-block dispatch window.
    const int sl   = (bx >> 3) & 3;
    const int rg   = ((bx >> 5) << 3) | (bx & 7);   // 0..1023
    const int m0   = rg * 64;
    const int b    = m0 >> 11;
    const int n_g  = sl * 128 + wave * 32 + l31;    // this lane's column

    // ---- breg preload: 32 x half8, lane-contiguous 1KB loads from L2
    const _Float16* bp = W1P + ((sl * 4 + wave) << 14) + hi * 256 + l31 * 8;
    half8 breg[32];
#pragma unroll
    for (int s = 0; s < 32; ++s)
        breg[s] = *(const half8*)(bp + s * 512);

    // ---- stage A: lane = row, wave covers cols [wave*128, wave*128+128)
    {
        const float* src = value + (size_t)(m0 + lane) * D_ + wave * 128;
#pragma unroll
        for (int b2 = 0; b2 < 2; ++b2) {
            floatx4 r[16];
#pragma unroll
            for (int i = 0; i < 16; ++i)
                r[i] = *(const floatx4*)(src + b2 * 64 + i * 4);
#pragma unroll
            for (int j = 0; j < 8; ++j) {
                half8 h;
#pragma unroll
                for (int q = 0; q < 4; ++q) {
                    h[q]     = (_Float16)r[2 * j][q];
                    h[4 + q] = (_Float16)r[2 * j + 1][q];
                }
                *(half8*)(&sA[((wave * 16 + b2 * 8 + j) * 64 + lane) * 8]) = h;
            }
        }
    }
    __syncthreads();   // the only staging barrier

    // ---- MFMA loop: zero global ops. 2 independent row-chunk chains.
    floatx16 acc0, acc1;
#pragma unroll
    for (int r = 0; r < 16; ++r) { acc0[r] = 0.f; acc1[r] = 0.f; }

#pragma unroll
    for (int s = 0; s < 32; ++s) {
        const int cc = (s * 2 + hi) * 64;
        const half8 af0 = *(const half8*)(&sA[(cc + l31) * 8]);
        const half8 af1 = *(const half8*)(&sA[(cc + 32 + l31) * 8]);
        acc0 = __builtin_amdgcn_mfma_f32_32x32x16_f16(af0, breg[s], acc0, 0, 0, 0);
        acc1 = __builtin_amdgcn_mfma_f32_32x32x16_f16(af1, breg[s], acc1, 0, 0, 0);
    }

    // ---- epilogue: ps = vv*tanh(acc + w2), reduce over 32 col-lanes
    const float w2 = w2q[b * U_ + n_g];
    const float vv = Vv[n_g];
    float ps0[16], ps1[16];
#pragma unroll
    for (int r = 0; r < 16; ++r) {
        ps0[r] = vv * tanh_fast(acc0[r] + w2);
        ps1[r] = vv * tanh_fast(acc1[r] + w2);
    }
#pragma unroll
    for (int off = 1; off < 32; off <<= 1)
#pragma unroll
        for (int r = 0; r < 16; ++r) {
            ps0[r] += __shfl_xor(ps0[r], off, 64);
            ps1[r] += __shfl_xor(ps1[r], off, 64);
        }

    if (l31 == 0) {
#pragma unroll
        for (int r = 0; r < 16; ++r) {
            const int row = (r & 3) + 8 * (r >> 2) + 4 * hi;  // C/D row map (validated)
            sRed[wave][row]      = ps0[r];
            sRed[wave][32 + row] = ps1[r];
        }
    }
    __syncthreads();
    if (tid < 64) {
        const float s = sRed[0][tid] + sRed[1][tid] + sRed[2][tid] + sRed[3][tid];
        u_part[(size_t)sl * M_ + m0 + tid] = s;
    }
}

// ---------------- k_post: softmax + top-4 + joint exact rescore + gather -------
__global__ __launch_bounds__(256)
void k_post(const float* __restrict__ u_part, const int* __restrict__ mask,
            const float* __restrict__ value, const float* __restrict__ W1,
            const float* __restrict__ w2q, const float* __restrict__ Vv,
            float* __restrict__ a_out, float* __restrict__ ctx_out) {
    __shared__ float sx[T_];
    __shared__ float rv[4];
    __shared__ int   ri[4];
    __shared__ float s_scalar;
    __shared__ int   s_cand[MAXC];
    __shared__ float s_score[MAXC];
    __shared__ __align__(16) float vrows[MAXC][D_];
    __shared__ int   s_t;

    const int b = blockIdx.x;
    const int tid = threadIdx.x;
    const int wave = tid >> 6, lane = tid & 63;

#pragma unroll
    for (int i = 0; i < 8; ++i) {
        const int t = tid * 8 + i;
        float x = u_part[b * T_ + t] + u_part[M_ + b * T_ + t]
                + u_part[2 * M_ + b * T_ + t] + u_part[3 * M_ + b * T_ + t];
        if (mask[b * T_ + t] == 0) x = -1e20f;
        sx[t] = x;
    }
    __syncthreads();

    for (int r = 0; r < MAXC; ++r) {
        float v = -INFINITY; int vi = 0;
#pragma unroll
        for (int i = 0; i < 8; ++i) {
            const int t = tid * 8 + i;
            const float x = sx[t];
            if (x > v) { v = x; vi = t; }
        }
        for (int off = 32; off > 0; off >>= 1) {
            const float ov = __shfl_down(v, off, 64);
            const int   oi = __shfl_down(vi, off, 64);
            if (ov > v || (ov == v && oi < vi)) { v = ov; vi = oi; }
        }
        if (lane == 0) { rv[wave] = v; ri[wave] = vi; }
        __syncthreads();
        if (tid == 0) {
            float bv = rv[0]; int bi = ri[0];
            for (int w = 1; w < 4; ++w)
                if (rv[w] > bv || (rv[w] == bv && ri[w] < bi)) { bv = rv[w]; bi = ri[w]; }
            s_cand[r] = bi;
            if (r == 0) s_scalar = bv;
            sx[bi] = -INFINITY;
        }
        __syncthreads();
    }
    const float mx = s_scalar;

    float zloc = 0.f;
    float evals[8];
#pragma unroll
    for (int i = 0; i < 8; ++i) {
        const int t = tid * 8 + i;
        float x = u_part[b * T_ + t] + u_part[M_ + b * T_ + t]
                + u_part[2 * M_ + b * T_ + t] + u_part[3 * M_ + b * T_ + t];
        if (mask[b * T_ + t] == 0) x = -1e20f;
        const float e = __expf(x - mx);
        evals[i] = e;
        zloc += e;
    }
    for (int off = 32; off > 0; off >>= 1) zloc += __shfl_down(zloc, off, 64);
    if (lane == 0) rv[wave] = zloc;
    __syncthreads();
    if (tid == 0) s_scalar = 1.0f / (rv[0] + rv[1] + rv[2] + rv[3]);
    __syncthreads();
    const float rz = s_scalar;
#pragma unroll
    for (int i = 0; i < 8; ++i) {
        const int t = tid * 8 + i;
        a_out[b * T_ + t] = evals[i] * rz;
    }

    // ---- joint exact fp32 rescore of the 4 candidates (one pass over W1) ----
#pragma unroll
    for (int ci = 0; ci < MAXC; ++ci) {
        const int t = s_cand[ci];
        vrows[ci][tid]       = value[((size_t)b * T_ + t) * D_ + tid];
        vrows[ci][tid + 256] = value[((size_t)b * T_ + t) * D_ + tid + 256];
    }
    __syncthreads();

    float dots[2][MAXC];
#pragma unroll
    for (int j = 0; j < 2; ++j)
#pragma unroll
        for (int ci = 0; ci < MAXC; ++ci) dots[j][ci] = 0.f;

    for (int d4 = 0; d4 < D_; d4 += 4) {
        floatx4 vr[MAXC];
#pragma unroll
        for (int ci = 0; ci < MAXC; ++ci)
            vr[ci] = *(const floatx4*)(&vrows[ci][d4]);
#pragma unroll
        for (int k = 0; k < 4; ++k) {
            const float w0 = W1[(size_t)(d4 + k) * U_ + tid];
            const float w1 = W1[(size_t)(d4 + k) * U_ + tid + 256];
#pragma unroll
            for (int ci = 0; ci < MAXC; ++ci) {
                dots[0][ci] = fmaf(vr[ci][k], w0, dots[0][ci]);
                dots[1][ci] = fmaf(vr[ci][k], w1, dots[1][ci]);
            }
        }
    }
    float sc[MAXC];
#pragma unroll
    for (int ci = 0; ci < MAXC; ++ci) {
        const float n0v = Vv[tid]       * tanhf(dots[0][ci] + w2q[b * U_ + tid]);
        const float n1v = Vv[tid + 256] * tanhf(dots[1][ci] + w2q[b * U_ + tid + 256]);
        sc[ci] = n0v + n1v;
    }
#pragma unroll
    for (int ci = 0; ci < MAXC; ++ci)
        for (int off = 32; off > 0; off >>= 1)
            sc[ci] += __shfl_down(sc[ci], off, 64);
    __syncthreads();
    if (lane == 0) {
#pragma unroll
        for (int ci = 0; ci < MAXC; ++ci)
            vrows[ci][wave] = sc[ci];
    }
    __syncthreads();
    if (tid == 0) {
#pragma unroll
        for (int ci = 0; ci < MAXC; ++ci) {
            const int t = s_cand[ci];
            float s = vrows[ci][0] + vrows[ci][1] + vrows[ci][2] + vrows[ci][3];
            if (mask[b * T_ + t] == 0) s = -1e20f;
            s_score[ci] = s;
        }
        float bv = s_score[0]; int bt = s_cand[0];
        for (int i = 1; i < MAXC; ++i) {
            if (s_score[i] > bv || (s_score[i] == bv && s_cand[i] < bt)) {
                bv = s_score[i]; bt = s_cand[i];
            }
        }
        s_t = bt;
    }
    __syncthreads();

    const int t = s_t;
    ctx_out[b * D_ + tid]       = value[((size_t)b * T_ + t) * D_ + tid];
    ctx_out[b * D_ + tid + 256] = value[((size_t)b * T_ + t) * D_ + tid + 256];
}

extern "C" void kernel_launch(void* const* d_in, const int* in_sizes, int n_in,
                              void* d_out, int out_size, void* d_ws, size_t ws_size,
                              hipStream_t stream) {
    const float* value = (const float*)d_in[0];   // [32,2048,512]
    const float* query = (const float*)d_in[1];   // [32,512]
    const int*   mask  = (const int*)d_in[2];     // [32,2048]
    const float* W1    = (const float*)d_in[3];   // [512,512]
    const float* W2    = (const float*)d_in[4];   // [512,512]
    const float* Vv    = (const float*)d_in[5];   // [512]

    char* ws = (char*)d_ws;
    _Float16* W1P    = (_Float16*)ws;                  //   524,288 B
    float*    w2q    = (float*)(ws + 524288);          //    65,536 B
    float*    u_part = (float*)(ws + 524288 + 65536);  // 1,048,576 B (4 x 65536 floats)

    float* ctx_out = (float*)d_out;              // [32,512]
    float* a_out   = (float*)d_out + B_ * D_;    // [32,2048]

    hipLaunchKernelGGL(k_prep,   dim3(192), dim3(256), 0, stream,
                       W1, query, W2, W1P, w2q);
    hipLaunchKernelGGL(k_gemm_u, dim3(NSPLIT * (M_ / 64)), dim3(256), 0, stream,
                       value, W1P, w2q, Vv, u_part);
    hipLaunchKernelGGL(k_post,   dim3(32), dim3(256), 0, stream,
                       u_part, mask, value, W1, w2q, Vv, a_out, ctx_out);
}